// Round 8
// baseline (257.463 us; speedup 1.0000x reference)
//
#include <hip/hip_runtime.h>

// Fused GQA attention block for MI355X (gfx950).
// cvt -> QKV GEMM (K-split z=2, bf16 partials, 2-stage dbuf gload_lds) ->
// rope_combine -> flash attention (8 waves/128 q-rows per block, kv-split NC=2,
// defer-max, swapped QK^T) -> attn_combine -> O-proj GEMM (K-split) -> o_combine.

#define S_LEN 2048
#define DIM_  2048
#define QK_LD 2560

typedef __attribute__((ext_vector_type(8))) __bf16 bf16x8;
typedef __attribute__((ext_vector_type(4))) float f32x4;
typedef __attribute__((ext_vector_type(4))) unsigned short us4;

__device__ __forceinline__ unsigned short f2bf(float f) {
    const __bf16 h = (__bf16)f;                 // hardware RNE
    return __builtin_bit_cast(unsigned short, h);
}
__device__ __forceinline__ float bf2f(unsigned short u) {
    union { unsigned u; float f; } v; v.u = ((unsigned)u) << 16;
    return v.f;
}

__device__ __forceinline__ void gload_lds16(const void* g, void* l) {
    __builtin_amdgcn_global_load_lds(
        (const __attribute__((address_space(1))) void*)g,
        (__attribute__((address_space(3))) void*)l, 16, 0, 0);
}

__device__ __forceinline__ int swz32(int r, int ch) { return r*32 + ((ch ^ ((r >> 1) & 3)) << 3); }
__device__ __forceinline__ int swz64(int r, int ch) { return r*64 + ((ch ^ (r & 7)) << 3); }

__global__ void cvt_all(const float* __restrict__ x,  const float* __restrict__ wq,
                        const float* __restrict__ wk, const float* __restrict__ wv,
                        const float* __restrict__ wo,
                        unsigned short* __restrict__ xb,
                        unsigned short* __restrict__ wqkv,
                        unsigned short* __restrict__ wob) {
    const int i4 = blockIdx.x * 256 + threadIdx.x;
    const float* src; unsigned short* dst; int off;
    if (i4 < 1048576)      { src = x;  dst = xb;             off = i4; }
    else if (i4 < 2097152) { src = wq; dst = wqkv;           off = i4 - 1048576; }
    else if (i4 < 2359296) { src = wk; dst = wqkv + 4194304; off = i4 - 2097152; }
    else if (i4 < 2621440) { src = wv; dst = wqkv + 5242880; off = i4 - 2359296; }
    else                   { src = wo; dst = wob;            off = i4 - 2621440; }
    const float4 v = reinterpret_cast<const float4*>(src)[off];
    us4 o = { f2bf(v.x), f2bf(v.y), f2bf(v.z), f2bf(v.w) };
    reinterpret_cast<us4*>(dst)[off] = o;
}

__global__ void build_bias(const float* __restrict__ qb, const float* __restrict__ kb,
                           const float* __restrict__ vb, float* __restrict__ out) {
    const int i = blockIdx.x * 256 + threadIdx.x;
    if (i < 2048) out[i] = qb[i];
    else if (i < 2560) out[i] = kb[i - 2048];
    else if (i < 3072) out[i] = vb[i - 2560];
}

// P[z][m][n] = sum_{k in z-half} A[m,k]*B[n,k], bf16 partial. 128^2 tile, BK=32,
// 2-stage dbuf via global_load_lds.
__global__ __launch_bounds__(256)
void gemm_part(const unsigned short* __restrict__ A,
               const unsigned short* __restrict__ B,
               unsigned short* __restrict__ P,
               int K, int ldc)
{
    __shared__ unsigned short As[2][128 * 32];
    __shared__ unsigned short Bs[2][128 * 32];
    const int t = threadIdx.x;
    const int lane = t & 63;
    const int w = t >> 6;
    const int wr = w >> 1, wc = w & 1;
    const int lq = lane & 15;
    const int g = lane >> 4;
    const int m0 = blockIdx.y * 128;
    const int n0 = blockIdx.x * 128;
    const int kbase = blockIdx.z * (K >> 1);
    const size_t zoff = (size_t)blockIdx.z * 2048 * ldc;

    const f32x4 z = {0.f, 0.f, 0.f, 0.f};
    f32x4 acc[4][4];
    #pragma unroll
    for (int i = 0; i < 4; i++)
        #pragma unroll
        for (int j = 0; j < 4; j++) acc[i][j] = z;

    auto stage = [&](int buf, int k0) {
        #pragma unroll
        for (int c = 0; c < 2; c++) {
            const int chunk = w * 128 + c * 64 + lane;
            const int r = chunk >> 2;
            const int chl = (chunk & 3) ^ ((r >> 1) & 3);
            gload_lds16(&A[(size_t)(m0 + r) * K + kbase + k0 + (chl << 3)],
                        &As[buf][(size_t)(w * 128 + c * 64) * 8]);
            gload_lds16(&B[(size_t)(n0 + r) * K + kbase + k0 + (chl << 3)],
                        &Bs[buf][(size_t)(w * 128 + c * 64) * 8]);
        }
    };

    const int NIT = K >> 6;
    stage(0, 0);
    for (int it = 0; it < NIT; ++it) {
        const int cur = it & 1;
        asm volatile("s_waitcnt vmcnt(0)" ::: "memory");
        __builtin_amdgcn_s_barrier();
        if (it + 1 < NIT) stage(cur ^ 1, (it + 1) << 5);
        bf16x8 a[4], b[4];
        #pragma unroll
        for (int mi = 0; mi < 4; mi++)
            a[mi] = *reinterpret_cast<const bf16x8*>(&As[cur][swz32(wr * 64 + mi * 16 + lq, g)]);
        #pragma unroll
        for (int ni = 0; ni < 4; ni++)
            b[ni] = *reinterpret_cast<const bf16x8*>(&Bs[cur][swz32(wc * 64 + ni * 16 + lq, g)]);
        #pragma unroll
        for (int mi = 0; mi < 4; mi++)
            #pragma unroll
            for (int ni = 0; ni < 4; ni++)
                acc[mi][ni] = __builtin_amdgcn_mfma_f32_16x16x32_bf16(a[mi], b[ni], acc[mi][ni], 0, 0, 0);
    }

    #pragma unroll
    for (int mi = 0; mi < 4; mi++) {
        const int row0 = m0 + wr * 64 + mi * 16 + g * 4;
        #pragma unroll
        for (int ni = 0; ni < 4; ni++) {
            const int col = n0 + wc * 64 + ni * 16 + lq;
            #pragma unroll
            for (int j = 0; j < 4; j++)
                P[zoff + (size_t)(row0 + j) * ldc + col] = f2bf(acc[mi][ni][j]);
        }
    }
}

// Combine QKV partials + bias, apply RoPE (+0.125*log2e fold into q), build
// qkbuf [2048][2560] and transposed V vtbuf [512][2048].
__global__ void rope_combine(const unsigned short* __restrict__ pq,
                             const float* __restrict__ bias,
                             const float* __restrict__ rope,
                             unsigned short* __restrict__ qk,
                             unsigned short* __restrict__ vt)
{
    const int idx = blockIdx.x * 256 + threadIdx.x;
    if (idx < 2621440) {
        const int s = idx / 1280;
        const int rem = idx - s * 1280;
        const int head = rem >> 5;
        const int p = rem & 31;
        const int col0 = head * 64 + p;
        const int col1 = col0 + 32;
        const size_t r0 = (size_t)s * 3072;
        const float v0 = bf2f(pq[r0 + col0]) + bf2f(pq[6291456 + r0 + col0]) + bias[col0];
        const float v1 = bf2f(pq[r0 + col1]) + bf2f(pq[6291456 + r0 + col1]) + bias[col1];
        const float c = rope[s * 128 + p];
        const float sn = rope[s * 128 + 64 + p];
        const float qs = (head < 32) ? 0.1803368801f : 1.0f;
        qk[(size_t)s * QK_LD + col0] = f2bf((v0 * c - v1 * sn) * qs);
        qk[(size_t)s * QK_LD + col1] = f2bf((v1 * c + v0 * sn) * qs);
    } else {
        const int i = idx - 2621440;
        const int d = i >> 9;
        const int s4 = (i & 511) << 2;
        const float bv = bias[2560 + d];
        us4 o;
        #pragma unroll
        for (int j = 0; j < 4; j++) {
            const size_t r = (size_t)(s4 + j) * 3072 + 2560 + d;
            o[j] = f2bf(bf2f(pq[r]) + bf2f(pq[6291456 + r]) + bv);
        }
        *reinterpret_cast<us4*>(&vt[(size_t)d * S_LEN + s4]) = o;
    }
}

// Flash attention: 8 waves, 128 q-rows per block (staging/barriers amortized 2x).
// kv-split NC=2: block (h, qc) with qp = 15-(qc>>1), c = qc&1 processes kv tiles
// tv ≡ c (mod 2), tv <= 2qp+1 -> exactly qp+1 tiles (balanced). Swapped QK^T:
// lane owns q-row qp*128 + w*16 + lq. Causal mask uses -INF (exact zero weight
// even for fully-masked tiles). Defer-max: skip rescale when no lane's max grew.
__global__ __launch_bounds__(512)
void attn_kernel(const unsigned short* __restrict__ qk,
                 const unsigned short* __restrict__ vt,
                 unsigned short* __restrict__ pacc,
                 float* __restrict__ pml)
{
    const int h = blockIdx.x;
    const int qc = blockIdx.y;                   // 0..31
    const int c = qc & 1;
    const int qp = 15 - (qc >> 1);               // longest-first
    const int hkv = h >> 2;
    const int t = threadIdx.x;
    const int lane = t & 63;
    const int w = t >> 6;                        // 0..7
    const int lq = lane & 15;
    const int g = lane >> 4;

    __shared__ unsigned short Ks[2][64 * 64];
    __shared__ unsigned short Vs[2][64 * 64];
    __shared__ unsigned short Ps[8][16 * 64];
    unsigned short* Pw = &Ps[w][0];

    const int qrow = qp * 128 + w * 16 + lq;

    bf16x8 aq[2];
    #pragma unroll
    for (int cc = 0; cc < 2; cc++)
        aq[cc] = *reinterpret_cast<const bf16x8*>(&qk[(size_t)qrow * QK_LD + h * 64 + cc * 32 + g * 8]);
    {   // force Q loads resolved pre-loop
        const uint4 u0 = reinterpret_cast<const uint4&>(aq[0]);
        const uint4 u1 = reinterpret_cast<const uint4&>(aq[1]);
        asm volatile("" :: "v"(u0.x), "v"(u0.y), "v"(u0.z), "v"(u0.w),
                           "v"(u1.x), "v"(u1.y), "v"(u1.z), "v"(u1.w));
    }

    const f32x4 z = {0.f, 0.f, 0.f, 0.f};
    f32x4 acc[4];
    #pragma unroll
    for (int df = 0; df < 4; df++) acc[df] = z;
    float m = -1e30f, l = 0.f;

    // stage tile tv: 512 threads x 1 chunk per array; linear LDS dest
    // (wave-uniform base), inverse-swizzled global source.
    auto stage = [&](int buf, int tv) {
        const int kv0 = tv * 64;
        const int r = t >> 3;
        const int chl = (t & 7) ^ (r & 7);
        gload_lds16(&qk[(size_t)(kv0 + r) * QK_LD + 2048 + hkv * 64 + (chl << 3)],
                    &Ks[buf][(size_t)w * 512]);
        gload_lds16(&vt[(size_t)(hkv * 64 + r) * S_LEN + kv0 + (chl << 3)],
                    &Vs[buf][(size_t)w * 512]);
    };

    const int ntile = qp + 1;
    stage(0, c);
    int cur = 0;
    for (int i = 0; i < ntile; ++i) {
        const int tv = c + 2 * i;
        asm volatile("s_waitcnt vmcnt(0)" ::: "memory");
        __builtin_amdgcn_s_barrier();
        if (i + 1 < ntile) stage(cur ^ 1, tv + 2);

        f32x4 sc[4];
        #pragma unroll
        for (int f = 0; f < 4; f++) {
            sc[f] = z;
            #pragma unroll
            for (int cc = 0; cc < 2; cc++) {
                const bf16x8 bk = *reinterpret_cast<const bf16x8*>(&Ks[cur][swz64(f * 16 + lq, cc * 4 + g)]);
                sc[f] = __builtin_amdgcn_mfma_f32_16x16x32_bf16(bk, aq[cc], sc[f], 0, 0, 0);
            }
        }

        // causal mask: kv_local = f*16 + g*4 + j; mask iff kv_global > qrow.
        const int thr = qrow - tv * 64 - g * 4;
        if (__any(thr < 51)) {
            #pragma unroll
            for (int f = 0; f < 4; f++)
                #pragma unroll
                for (int j = 0; j < 4; j++)
                    if (f * 16 + j > thr) sc[f][j] = -__builtin_inff();
        }

        float mx = sc[0][0];
        #pragma unroll
        for (int f = 0; f < 4; f++)
            #pragma unroll
            for (int j = 0; j < 4; j++) mx = fmaxf(mx, sc[f][j]);
        mx = fmaxf(mx, __shfl_xor(mx, 16));
        mx = fmaxf(mx, __shfl_xor(mx, 32));

        const bool need = !__all(mx <= m);       // defer-max: exact skip
        const float mn = need ? fmaxf(m, mx) : m;
        float s = 0.f;
        #pragma unroll
        for (int f = 0; f < 4; f++)
            #pragma unroll
            for (int j = 0; j < 4; j++) {
                const float p = exp2f(sc[f][j] - mn);
                sc[f][j] = p;
                s += p;
            }
        s += __shfl_xor(s, 16);
        s += __shfl_xor(s, 32);
        if (need) {
            const float rs = exp2f(m - mn);
            m = mn;
            l = l * rs + s;
            #pragma unroll
            for (int df = 0; df < 4; df++) acc[df] *= rs;
        } else {
            l += s;
        }

        #pragma unroll
        for (int f = 0; f < 4; f++) {
            us4 pk = { f2bf(sc[f][0]), f2bf(sc[f][1]), f2bf(sc[f][2]), f2bf(sc[f][3]) };
            *reinterpret_cast<us4*>(
                &Pw[lq * 64 + ((((f << 1) | (g >> 1)) ^ (lq & 7)) << 3) + ((g & 1) << 2)]) = pk;
        }
        #pragma unroll
        for (int cc = 0; cc < 2; cc++) {
            const bf16x8 pb = *reinterpret_cast<const bf16x8*>(
                &Pw[lq * 64 + (((cc * 4 + g) ^ (lq & 7)) << 3)]);
            #pragma unroll
            for (int df = 0; df < 4; df++) {
                const bf16x8 bv = *reinterpret_cast<const bf16x8*>(&Vs[cur][swz64(df * 16 + lq, cc * 4 + g)]);
                acc[df] = __builtin_amdgcn_mfma_f32_16x16x32_bf16(bv, pb, acc[df], 0, 0, 0);
            }
        }
        cur ^= 1;
    }

    const size_t rbase = ((size_t)(h * 2 + c) * 2048 + qrow);
    #pragma unroll
    for (int df = 0; df < 4; df++) {
        us4 pk = { f2bf(acc[df][0]), f2bf(acc[df][1]), f2bf(acc[df][2]), f2bf(acc[df][3]) };
        *reinterpret_cast<us4*>(&pacc[rbase * 64 + df * 16 + g * 4]) = pk;
    }
    if (g == 0) {
        pml[rbase * 2]     = m;
        pml[rbase * 2 + 1] = l;
    }
}

__global__ void attn_combine(const unsigned short* __restrict__ pacc,
                             const float* __restrict__ pml,
                             const float* __restrict__ sinks,
                             unsigned short* __restrict__ abuf) {
    const int idx = blockIdx.x * 256 + threadIdx.x;      // 2048*32*4
    const int q4 = idx & 3;
    const int row = (idx >> 2) & 2047;
    const int h = idx >> 13;
    const size_t r0 = (size_t)(h * 2 + 0) * 2048 + row;
    const size_t r1 = (size_t)(h * 2 + 1) * 2048 + row;
    const float m0 = pml[r0 * 2], l0 = pml[r0 * 2 + 1];
    const float m1 = pml[r1 * 2], l1 = pml[r1 * 2 + 1];
    const float M = fmaxf(m0, m1);
    const float w0 = exp2f(m0 - M), w1 = exp2f(m1 - M);
    const float L = l0 * w0 + l1 * w1;
    const float lse = 0.6931471806f * (M + log2f(L));
    const float d = sinks[h] - lse;
    float f = (d > 20.f) ? d : log1pf(__expf(d));
    if (f > 20.f) f = 20.f;
    const float fac = __expf(-f) / L;
    const unsigned short* a0 = &pacc[r0 * 64 + q4 * 16];
    const unsigned short* a1 = &pacc[r1 * 64 + q4 * 16];
    unsigned short* dst = &abuf[(size_t)row * DIM_ + h * 64 + q4 * 16];
    #pragma unroll
    for (int k = 0; k < 4; k++) {
        const us4 x0 = *reinterpret_cast<const us4*>(&a0[k * 4]);
        const us4 x1 = *reinterpret_cast<const us4*>(&a1[k * 4]);
        us4 r;
        #pragma unroll
        for (int j = 0; j < 4; j++)
            r[j] = f2bf((bf2f(x0[j]) * w0 + bf2f(x1[j]) * w1) * fac);
        *reinterpret_cast<us4*>(&dst[k * 4]) = r;
    }
}

__global__ void o_combine(const unsigned short* __restrict__ po,
                          const float* __restrict__ ob,
                          float* __restrict__ out) {
    const int idx = blockIdx.x * 256 + threadIdx.x;      // 2048*512
    const int row = idx >> 9;
    const int c4 = (idx & 511) << 2;
    float4 o;
    const size_t r = (size_t)row * 2048 + c4;
    const us4 x0 = *reinterpret_cast<const us4*>(&po[r]);
    const us4 x1 = *reinterpret_cast<const us4*>(&po[4194304 + r]);
    o.x = bf2f(x0[0]) + bf2f(x1[0]) + ob[c4];
    o.y = bf2f(x0[1]) + bf2f(x1[1]) + ob[c4 + 1];
    o.z = bf2f(x0[2]) + bf2f(x1[2]) + ob[c4 + 2];
    o.w = bf2f(x0[3]) + bf2f(x1[3]) + ob[c4 + 3];
    *reinterpret_cast<float4*>(&out[r]) = o;
}

extern "C" void kernel_launch(void* const* d_in, const int* in_sizes, int n_in,
                              void* d_out, int out_size, void* d_ws, size_t ws_size,
                              hipStream_t stream) {
    const float* x     = (const float*)d_in[0];
    const float* rope  = (const float*)d_in[1];
    const float* wq_w  = (const float*)d_in[2];
    const float* wq_b  = (const float*)d_in[3];
    const float* wk_w  = (const float*)d_in[4];
    const float* wk_b  = (const float*)d_in[5];
    const float* wv_w  = (const float*)d_in[6];
    const float* wv_b  = (const float*)d_in[7];
    const float* wo_w  = (const float*)d_in[8];
    const float* wo_b  = (const float*)d_in[9];
    const float* sinks = (const float*)d_in[10];
    float* out = (float*)d_out;

    // ws layout (MB offsets, dead-region reuse):
    //  0: xb(8) -> qkbuf(10) -> po(16)        8: wqkv(12)   10: vtbuf(2)
    // 20: wob(8, live)                        28: pq(24) -> pacc(16)
    // 44: pml(2)   46: abuf(8)   54: bcat
    char* ws = (char*)d_ws;
    unsigned short* xb    = (unsigned short*)(ws);
    unsigned short* wqkv  = (unsigned short*)(ws + (8u  << 20));
    unsigned short* wob   = (unsigned short*)(ws + (20u << 20));
    unsigned short* pq    = (unsigned short*)(ws + (28u << 20));
    unsigned short* qkbuf = (unsigned short*)(ws);
    unsigned short* vtbuf = (unsigned short*)(ws + (10u << 20));
    unsigned short* pacc  = (unsigned short*)(ws + (28u << 20));
    float*          pml   = (float*)(ws + (44u << 20));
    unsigned short* abuf  = (unsigned short*)(ws + (46u << 20));
    unsigned short* po    = (unsigned short*)(ws);
    float*          bcat  = (float*)(ws + (54u << 20));

    cvt_all<<<14336, 256, 0, stream>>>(x, wq_w, wk_w, wv_w, wo_w, xb, wqkv, wob);
    build_bias<<<12, 256, 0, stream>>>(wq_b, wk_b, wv_b, bcat);

    gemm_part<<<dim3(24, 16, 2), 256, 0, stream>>>(xb, wqkv, pq, 2048, 3072);
    rope_combine<<<11264, 256, 0, stream>>>(pq, bcat, rope, qkbuf, vtbuf);
    attn_kernel<<<dim3(32, 32), 512, 0, stream>>>(qkbuf, vtbuf, pacc, pml);
    attn_combine<<<1024, 256, 0, stream>>>(pacc, pml, sinks, abuf);
    gemm_part<<<dim3(16, 16, 2), 256, 0, stream>>>(abuf, wob, po, 2048, 2048);
    o_combine<<<4096, 256, 0, stream>>>(po, wo_b, out);
}